// Round 1
// baseline (105.699 us; speedup 1.0000x reference)
//
#include <hip/hip_runtime.h>
#include <cstdint>
#include <cstddef>

// Problem constants
#define NB 2
#define NF 8
#define NS 4
#define NK 90      // real K (dirs per shell)
#define NP 642     // grid vertices (M)
#define NXYZ 1728  // 12*12*12 (N)
#define KP 96      // K padded to multiple of 32
#define MT 64      // p-tile
#define NT 192     // xyz-tile (1728 = 9*192 exact)
#define PTILES 11  // ceil(642/64)
#define NTILES 9
#define ROWB (KP * 2)  // LDS row stride in bytes (96 bf16)

typedef __attribute__((ext_vector_type(8))) __bf16 bf16x8;
typedef __attribute__((ext_vector_type(4))) float f32x4;
typedef __attribute__((ext_vector_type(4))) uint32_t u32x4;

// RNE pack of two f32 -> u32 holding 2 bf16
__device__ __forceinline__ uint32_t pack2bf(float a, float b) {
    uint32_t ua = __builtin_bit_cast(uint32_t, a);
    uint32_t ub = __builtin_bit_cast(uint32_t, b);
    ua += 0x7FFFu + ((ua >> 16) & 1u);
    ub += 0x7FFFu + ((ub >> 16) & 1u);
    return (ua >> 16) | (ub & 0xFFFF0000u);
}

__global__ __launch_bounds__(192) void interp_mfma(
    const float* __restrict__ x, const float* __restrict__ Wm,
    float* __restrict__ y)
{
    // XOR-swizzled LDS tiles: full byte-offset ^= ((row&7)<<4).
    // Bijective for 192B row stride (XOR stays within shared 128B blocks
    // only across even->odd row boundaries where bit6 differs).
    __shared__ __align__(16) char As[MT * ROWB];  // 12 KB  A = W[s]^T  [p][k]
    __shared__ __align__(16) char Bs[NT * ROWB];  // 36 KB  B^T        [xyz][k]

    int blk = (int)blockIdx.x;
    const int pt = blk % PTILES; blk /= PTILES;   // p-tile fastest: 11 consecutive
    const int nt = blk % NTILES; blk /= NTILES;   // blocks share the same x columns
    const int f  = blk % NF;     blk /= NF;
    const int s  = blk % NS;     blk /= NS;
    const int b  = blk;

    const int tid = (int)threadIdx.x;
    const int p0 = pt * MT;
    const int n0 = nt * NT;

    // ---- Stage A: As[r][k] = bf16(W[s][k][p0+r]), k in [0,96), zero-padded.
    // Wave w handles k-block [w*32, w*32+32); lanes r consecutive -> coalesced.
    {
        const int r  = tid & 63;
        const int kc = tid >> 6;  // 0..2
        const int p  = p0 + r;
        const bool pv = (p < NP);
        const float* wp = Wm + (size_t)s * NK * NP + p;
        const int rs = (r & 7) << 4;
        #pragma unroll
        for (int kk = 0; kk < 32; kk += 8) {
            const int kb = kc * 32 + kk;
            float v[8];
            #pragma unroll
            for (int j = 0; j < 8; ++j) {
                const int k = kb + j;
                v[j] = (pv && (k < NK)) ? wp[(size_t)k * NP] : 0.f;
            }
            u32x4 u;
            u.x = pack2bf(v[0], v[1]);
            u.y = pack2bf(v[2], v[3]);
            u.z = pack2bf(v[4], v[5]);
            u.w = pack2bf(v[6], v[7]);
            *(u32x4*)(As + ((r * ROWB + kb * 2) ^ rs)) = u;
        }
    }

    // ---- Stage B: Bs[c][k] = bf16(x[b,f,s*90+k, n0+c]) — B^T so frag loads are
    // contiguous 8-k ds_read_b128. Loads coalesced across lanes (c consecutive).
    {
        const int c = tid;  // 0..191, n0+c < 1728 always (9*192 exact)
        const float* xp = x + (((size_t)b * NF + f) * (NS * NK) + (size_t)s * NK) * NXYZ
                            + n0 + c;
        const int cs = (c & 7) << 4;
        #pragma unroll
        for (int kb = 0; kb < KP; kb += 8) {
            float v[8];
            #pragma unroll
            for (int j = 0; j < 8; ++j) {
                const int k = kb + j;
                v[j] = (k < NK) ? xp[(size_t)k * NXYZ] : 0.f;
            }
            u32x4 u;
            u.x = pack2bf(v[0], v[1]);
            u.y = pack2bf(v[2], v[3]);
            u.z = pack2bf(v[4], v[5]);
            u.w = pack2bf(v[6], v[7]);
            *(u32x4*)(Bs + ((c * ROWB + kb * 2) ^ cs)) = u;
        }
    }

    __syncthreads();

    // ---- Compute: wave w owns n-slice [w*64, w*64+64); full 64 p rows.
    // 4 m-frags x 4 n-frags x 3 k-steps = 48 MFMA / wave.
    const int lane = tid & 63;
    const int w  = tid >> 6;
    const int lr = lane & 15;
    const int lg = lane >> 4;
    const int ls = (lr & 7) << 4;  // row&7 == lr&7 for all frag rows (bases mult of 16)

    f32x4 acc[4][4];
    #pragma unroll
    for (int mi = 0; mi < 4; ++mi)
        #pragma unroll
        for (int ni = 0; ni < 4; ++ni)
            acc[mi][ni] = (f32x4){0.f, 0.f, 0.f, 0.f};

    #pragma unroll
    for (int kk = 0; kk < 3; ++kk) {
        const int kbyte = kk * 64 + lg * 16;  // (lane>>4)*8 bf16 within k-step
        bf16x8 a[4], bb[4];
        #pragma unroll
        for (int mi = 0; mi < 4; ++mi) {
            const int row = mi * 16 + lr;
            a[mi] = *(const bf16x8*)(As + ((row * ROWB + kbyte) ^ ls));
        }
        #pragma unroll
        for (int ni = 0; ni < 4; ++ni) {
            const int row = w * 64 + ni * 16 + lr;
            bb[ni] = *(const bf16x8*)(Bs + ((row * ROWB + kbyte) ^ ls));
        }
        #pragma unroll
        for (int mi = 0; mi < 4; ++mi)
            #pragma unroll
            for (int ni = 0; ni < 4; ++ni)
                acc[mi][ni] = __builtin_amdgcn_mfma_f32_16x16x32_bf16(
                    a[mi], bb[ni], acc[mi][ni], 0, 0, 0);
    }

    // ---- Store: C row = p (m), col = xyz (n). col = lane&15 -> 64B segments.
    const size_t chan = (size_t)b * (NS * NF) + (size_t)s * NF + f;
    float* ybase = y + chan * ((size_t)NP * NXYZ);
    const int colbase = n0 + w * 64 + lr;
    #pragma unroll
    for (int mi = 0; mi < 4; ++mi) {
        const int prow = p0 + mi * 16 + lg * 4;
        #pragma unroll
        for (int r = 0; r < 4; ++r) {
            const int p = prow + r;
            if (p < NP) {
                float* dst = ybase + (size_t)p * NXYZ + colbase;
                #pragma unroll
                for (int ni = 0; ni < 4; ++ni)
                    dst[ni * 16] = acc[mi][ni][r];
            }
        }
    }
}

extern "C" void kernel_launch(void* const* d_in, const int* in_sizes, int n_in,
                              void* d_out, int out_size, void* d_ws, size_t ws_size,
                              hipStream_t stream) {
    (void)in_sizes; (void)n_in; (void)d_ws; (void)ws_size; (void)out_size;
    const float* x  = (const float*)d_in[0];
    const float* Wm = (const float*)d_in[1];
    // d_in[2] (shell_inverse) is sorted contiguous by construction -> static layout.
    float* y = (float*)d_out;
    dim3 grid(NB * NS * NF * NTILES * PTILES);  // 6336
    interp_mfma<<<grid, 192, 0, stream>>>(x, Wm, y);
}